// Round 6
// baseline (138.952 us; speedup 1.0000x reference)
//
#include <hip/hip_runtime.h>
#include <stdint.h>

#define S_LEN 2048
#define DMODEL 1024
#define NHEAD 16
#define HDIM 64
#define NE 3072
#define C2 0.18033688011112042f  // 0.125 * log2(e)

typedef __attribute__((ext_vector_type(8))) short short8_t;
typedef __attribute__((ext_vector_type(4))) float f32x4;

__device__ __forceinline__ float bf2f(ushort u) {
  union { float f; uint32_t i; } c; c.i = ((uint32_t)u) << 16; return c.f;
}
__device__ __forceinline__ ushort f2bf(float f) {
  union { float f; uint32_t i; } c; c.f = f;
  uint32_t x = c.i;
  return (ushort)((x + 0x7fffu + ((x >> 16) & 1u)) >> 16);
}

__device__ __forceinline__ void gload_lds16(const ushort* g, ushort* l) {
  __builtin_amdgcn_global_load_lds(
      (const __attribute__((address_space(1))) void*)g,
      (__attribute__((address_space(3))) void*)l, 16, 0, 0);
}

// ---------------- fused fp32 -> bf16 convert (x, w_in, w_out) ----------------
__global__ void cvt_all(const float* __restrict__ x, const float* __restrict__ w_in,
                        const float* __restrict__ w_out,
                        ushort* __restrict__ xbf, ushort* __restrict__ winbf,
                        ushort* __restrict__ woutbf) {
  int i = blockIdx.x * blockDim.x + threadIdx.x;
  const float* src; ushort* dst; int off;
  if (i < 524288)       { src = x;     dst = xbf;    off = i; }
  else if (i < 1310720) { src = w_in;  dst = winbf;  off = i - 524288; }
  else                  { src = w_out; dst = woutbf; off = i - 1310720; }
  float4 v = ((const float4*)src)[off];
  ushort4 o;
  o.x = f2bf(v.x); o.y = f2bf(v.y); o.z = f2bf(v.z); o.w = f2bf(v.w);
  ((ushort4*)dst)[off] = o;
}

// ---------------- bf16 GEMM: C[M][N] = A[M][K] * B[N][K]^T ----------------
// XCD-swizzled block id (grid % 8 == 0 for all our launches).
template<int BM, int BN, int OUT_BF16>
__global__ __launch_bounds__(256) void gemm_abt(
    const ushort* __restrict__ A, const ushort* __restrict__ B,
    void* __restrict__ Cv, int M, int N, int K)
{
  constexpr int AR = BM / 32;
  constexpr int AC = BN / 32;
  constexpr int NG = (BM + BN) / 16;
  constexpr int PG = NG / 4;
  __shared__ ushort lds[(BM + BN) * 32];

  const int nbn = N / BN;
  const int cpx = gridDim.x >> 3;
  const int bid = blockIdx.x;
  const int swz = (bid & 7) * cpx + (bid >> 3);
  const int bm = swz / nbn;
  const int bn = swz - bm * nbn;
  const int tid = threadIdx.x;
  const int w = tid >> 6, l = tid & 63;
  const int wm = w >> 1, wn = w & 1;
  const int fr = l & 15, fg = l >> 4;

  f32x4 acc[AR][AC];
#pragma unroll
  for (int r = 0; r < AR; ++r)
#pragma unroll
    for (int c = 0; c < AC; ++c) acc[r][c] = (f32x4){0.f, 0.f, 0.f, 0.f};

  const ushort* gsrc[PG];
  ushort* ldst[PG];
#pragma unroll
  for (int i = 0; i < PG; ++i) {
    int c = w + 4 * i;
    if (c < BM / 16) {
      gsrc[i] = A + (size_t)(bm * BM + c * 16 + (l >> 2)) * K + (l & 3) * 8;
      ldst[i] = &lds[c * 512];
    } else {
      int c2 = c - BM / 16;
      gsrc[i] = B + (size_t)(bn * BN + c2 * 16 + (l >> 2)) * K + (l & 3) * 8;
      ldst[i] = &lds[BM * 32 + c2 * 512];
    }
  }

  const ushort* fa = &lds[(wm * (BM / 2) + fr) * 32 + fg * 8];
  const ushort* fb = &lds[BM * 32 + (wn * (BN / 2) + fr) * 32 + fg * 8];

  for (int k0 = 0; k0 < K; k0 += 32) {
    __syncthreads();
#pragma unroll
    for (int i = 0; i < PG; ++i) gload_lds16(gsrc[i] + k0, ldst[i]);
    __syncthreads();

    short8_t af[AR], bfr[AC];
#pragma unroll
    for (int r = 0; r < AR; ++r) {
      union { short8_t v; uint4 q; } u;
      u.q = *(const uint4*)(fa + r * 512);
      af[r] = u.v;
    }
#pragma unroll
    for (int c = 0; c < AC; ++c) {
      union { short8_t v; uint4 q; } u;
      u.q = *(const uint4*)(fb + c * 512);
      bfr[c] = u.v;
    }
    __builtin_amdgcn_s_setprio(1);
#pragma unroll
    for (int r = 0; r < AR; ++r)
#pragma unroll
      for (int c = 0; c < AC; ++c)
        acc[r][c] = __builtin_amdgcn_mfma_f32_16x16x32_bf16(af[r], bfr[c], acc[r][c], 0, 0, 0);
    __builtin_amdgcn_s_setprio(0);
  }

  const int row0 = bm * BM + wm * (BM / 2) + fg * 4;
  const int col0 = bn * BN + wn * (BN / 2) + fr;
#pragma unroll
  for (int r = 0; r < AR; ++r)
#pragma unroll
    for (int c = 0; c < AC; ++c)
#pragma unroll
      for (int j = 0; j < 4; ++j) {
        int row = row0 + r * 16 + j;
        int col = col0 + c * 16;
        if (OUT_BF16)
          ((ushort*)Cv)[(size_t)row * N + col] = f2bf(acc[r][c][j]);
        else
          ((float*)Cv)[(size_t)row * N + col] = acc[r][c][j];
      }
}

// ---------------- RoPE cos/sin table: tab[srow*32 + i] = {cos, sin} ----------------
__global__ void rope_tab(float2* __restrict__ tab) {
  int idx = blockIdx.x * 256 + threadIdx.x;  // 65536
  int srow = idx >> 5, i = idx & 31;
  float invf = exp2f((float)i * (-13.287712379549449f / 32.f));
  float sn, c;
  sincosf((float)srow * invf, &sn, &c);
  tab[idx] = make_float2(c, sn);
}

// ---------------- RoPE in-place on Q and K sections of qkv ----------------
__global__ void rope_kernel(ushort* __restrict__ qkv, const float2* __restrict__ tab) {
  int idx = blockIdx.x * blockDim.x + threadIdx.x;
  int i = idx & 31;
  int hh = (idx >> 5) & (NHEAD - 1);
  int sec = (idx >> 9) & 1;
  int srow = idx >> 10;
  float2 cs = tab[(srow << 5) + i];
  size_t base = (size_t)srow * NE + (size_t)sec * DMODEL + hh * HDIM;
  float x1 = bf2f(qkv[base + i]);
  float x2 = bf2f(qkv[base + i + 32]);
  qkv[base + i]      = f2bf(x1 * cs.x - x2 * cs.y);
  qkv[base + i + 32] = f2bf(x2 * cs.x + x1 * cs.y);
}

// ---------------- V transpose: qkv V-section -> vt[h][d][key] ----------------
__global__ __launch_bounds__(256) void transpose_v(
    const ushort* __restrict__ qkv, ushort* __restrict__ vt)
{
  __shared__ ushort t[64][72];
  const int h = blockIdx.x & 15, c = blockIdx.x >> 4;
  const int tid = threadIdx.x;
#pragma unroll
  for (int j = 0; j < 2; ++j) {
    int idx = tid + 256 * j;
    int key = idx >> 3, d8 = (idx & 7) << 3;
    uint4 v = *(const uint4*)(qkv + (size_t)(c * 64 + key) * NE + 2 * DMODEL + h * HDIM + d8);
    *(uint4*)&t[key][d8] = v;
  }
  __syncthreads();
#pragma unroll
  for (int j = 0; j < 2; ++j) {
    int idx = tid + 256 * j;
    int d = idx >> 3, k8 = (idx & 7) << 3;
    ushort tmp[8];
#pragma unroll
    for (int i = 0; i < 8; ++i) tmp[i] = t[k8 + i][d];
    *(uint4*)(vt + (size_t)(h * 64 + d) * S_LEN + c * 64 + k8) = *(const uint4*)tmp;
  }
}

// ---------------- MFMA flash attention: barrier-free, wave-autonomous ----------------
// 896 blocks = 56 items x 16 heads; 4 independent waves/block, 16 q-rows each.
// K and V^T fragments loaded directly from global (L2-resident) as b128 per lane.
// Only LDS: wave-private 2KB P bounce. No __syncthreads anywhere.
__global__ __launch_bounds__(256) void attn_mfma(
    const ushort* __restrict__ qkv, const ushort* __restrict__ vt,
    ushort* __restrict__ O, ushort* __restrict__ po, float2* __restrict__ pmd,
    const int* __restrict__ icausal)
{
  __shared__ __align__(16) ushort P0[4096];  // 8KB: 4 waves x 2KB

  const int h = blockIdx.x & 15;
  const int i = blockIdx.x >> 4;
  const int j = (i < 8) ? (15 - i) : (i < 48) ? (63 - i) : (55 - i);  // longest-first
  int rb4, ns, s;
  if (j < 16)      { rb4 = j; ns = 1; s = 0; }
  else if (j < 32) { rb4 = 16 + ((j - 16) >> 1); ns = 2; s = (j - 16) & 1; }
  else             { int jj = j - 32; int q3 = jj / 3; rb4 = 24 + q3; ns = 3; s = jj - q3 * 3; }

  const int causal = *icausal;
  const int nt = causal ? (rb4 + 1) : (S_LEN / 64);
  const int t0 = s * nt / ns, t1 = (s + 1) * nt / ns;

  const int tid = threadIdx.x;
  const int w = tid >> 6, l = tid & 63;
  const int lq = l & 15, g = l >> 4;
  const int q0w = rb4 * 64 + w * 16;
  const int xsw = (lq & 7) << 4;

  short8_t qf[2];
  {
    const ushort* qp = qkv + (size_t)(q0w + lq) * NE + h * HDIM;
    union { short8_t v; uint4 q; } u0, u1;
    u0.q = *(const uint4*)(qp + 8 * g);
    u1.q = *(const uint4*)(qp + 32 + 8 * g);
    qf[0] = u0.v; qf[1] = u1.v;
  }

  float m_run = -1e30f, den = 0.f;
  f32x4 oacc[4];
#pragma unroll
  for (int k = 0; k < 4; ++k) oacc[k] = (f32x4){0.f, 0.f, 0.f, 0.f};

  char* const Pb = (char*)P0 + w * 2048;
  // per-lane fragment base pointers (advance per tile)
  const ushort* kb = qkv + (size_t)(t0 * 64 + lq) * NE + DMODEL + h * HDIM + 8 * g;
  const ushort* vb = vt + (size_t)(h * 64 + lq) * S_LEN + t0 * 64 + 8 * g;

  for (int t = t0; t < t1; ++t) {
    const int k0 = t * 64;
    // issue all K and V^T fragment loads up front; V stays in flight through softmax
    uint4 kq[8], vq[8];
#pragma unroll
    for (int st = 0; st < 4; ++st)
#pragma unroll
      for (int dh = 0; dh < 2; ++dh)
        kq[st * 2 + dh] = *(const uint4*)(kb + (size_t)st * 16 * NE + dh * 32);
#pragma unroll
    for (int d2 = 0; d2 < 4; ++d2)
#pragma unroll
      for (int kk = 0; kk < 2; ++kk)
        vq[d2 * 2 + kk] = *(const uint4*)(vb + (size_t)d2 * 16 * S_LEN + kk * 32);
    kb += (size_t)64 * NE; vb += 64;

    f32x4 sacc[4];
#pragma unroll
    for (int st = 0; st < 4; ++st) sacc[st] = (f32x4){0.f, 0.f, 0.f, 0.f};
    __builtin_amdgcn_s_setprio(1);
#pragma unroll
    for (int dh = 0; dh < 2; ++dh)
#pragma unroll
      for (int st = 0; st < 4; ++st) {
        union { short8_t v; uint4 q; } u;
        u.q = kq[st * 2 + dh];
        sacc[st] = __builtin_amdgcn_mfma_f32_16x16x32_bf16(u.v, qf[dh], sacc[st], 0, 0, 0);
      }
    __builtin_amdgcn_s_setprio(0);

    // mask + row max (in place)
    float vmax = -3e38f;
    const bool domask = causal && (t == rb4);
#pragma unroll
    for (int st = 0; st < 4; ++st)
#pragma unroll
      for (int r = 0; r < 4; ++r) {
        float sv = sacc[st][r];
        if (domask && (k0 + st * 16 + 4 * g + r > q0w + lq)) sv = -3e38f;
        sacc[st][r] = sv;
        vmax = fmaxf(vmax, sv);
      }
    vmax = fmaxf(vmax, __shfl_xor(vmax, 16));
    vmax = fmaxf(vmax, __shfl_xor(vmax, 32));

    // defer-rescale (T13)
    if (__any(vmax > m_run + 44.3614196f)) {   // 8 / C2
      float mn = fmaxf(m_run, vmax);
      float alpha = exp2f((m_run - mn) * C2);
      den *= alpha;
#pragma unroll
      for (int k = 0; k < 4; ++k) {
        oacc[k][0] *= alpha; oacc[k][1] *= alpha;
        oacc[k][2] *= alpha; oacc[k][3] *= alpha;
      }
      m_run = mn;
    }
    float mc2 = m_run * C2;
    float psum = 0.f;
#pragma unroll
    for (int st = 0; st < 4; ++st)
#pragma unroll
      for (int r = 0; r < 4; ++r) {
        float p = exp2f(fmaf(sacc[st][r], C2, -mc2));
        psum += p;
        sacc[st][r] = p;
      }
#pragma unroll
    for (int st = 0; st < 4; ++st) {
      uint d0, d1;
      asm("v_cvt_pk_bf16_f32 %0, %1, %2" : "=v"(d0) : "v"(sacc[st][0]), "v"(sacc[st][1]));
      asm("v_cvt_pk_bf16_f32 %0, %1, %2" : "=v"(d1) : "v"(sacc[st][2]), "v"(sacc[st][3]));
      uint2 dd; dd.x = d0; dd.y = d1;
      *(uint2*)(Pb + ((lq * 128 + (st * 16 + 4 * g) * 2) ^ xsw)) = dd;
    }
    psum += __shfl_xor(psum, 16);
    psum += __shfl_xor(psum, 32);
    den += psum;

    __builtin_amdgcn_s_setprio(1);
#pragma unroll
    for (int kk = 0; kk < 2; ++kk) {
      union { short8_t v; uint4 q; } pu;
      pu.q = *(const uint4*)(Pb + ((lq * 128 + (kk * 32 + 8 * g) * 2) ^ xsw));
#pragma unroll
      for (int d2 = 0; d2 < 4; ++d2) {
        union { short8_t v; uint4 q; } vu;
        vu.q = vq[d2 * 2 + kk];
        oacc[d2] = __builtin_amdgcn_mfma_f32_16x16x32_bf16(vu.v, pu.v, oacc[d2], 0, 0, 0);
      }
    }
    __builtin_amdgcn_s_setprio(0);
  }

  if (ns > 1) {
    const int slot = (rb4 < 24) ? ((rb4 - 16) * 2 + s) : (16 + (rb4 - 24) * 3 + s);
    const int qi = w * 16 + lq;
    ushort* base = po + ((size_t)(h * 40 + slot) * 64 + qi) * 64;
#pragma unroll
    for (int d2 = 0; d2 < 4; ++d2) {
      uint d0, d1;
      asm("v_cvt_pk_bf16_f32 %0, %1, %2" : "=v"(d0) : "v"(oacc[d2][0]), "v"(oacc[d2][1]));
      asm("v_cvt_pk_bf16_f32 %0, %1, %2" : "=v"(d1) : "v"(oacc[d2][2]), "v"(oacc[d2][3]));
      uint2 dd; dd.x = d0; dd.y = d1;
      *(uint2*)(base + d2 * 16 + 4 * g) = dd;
    }
    if (g == 0) pmd[(h * 40 + slot) * 64 + qi] = make_float2(m_run, den);
  } else {
    float inv = 1.f / den;
#pragma unroll
    for (int d2 = 0; d2 < 4; ++d2)
#pragma unroll
      for (int r = 0; r < 4; ++r) {
        int d = d2 * 16 + 4 * g + r;
        *(ushort*)(Pb + ((lq * 128 + d * 2) ^ xsw)) = f2bf(oacc[d2][r] * inv);
      }
#pragma unroll
    for (int jj = 0; jj < 2; ++jj) {
      int idx = l + 64 * jj;
      int q = idx >> 3, seg = idx & 7;
      uint4 val = *(const uint4*)(Pb + ((q * 128 + seg * 16) ^ ((q & 7) << 4)));
      *(uint4*)(O + (size_t)(q0w + q) * DMODEL + h * HDIM + seg * 8) = val;
    }
  }
}

// ---------------- combine key-slices for q rows 1024..2047 ----------------
__global__ __launch_bounds__(256) void attn_combine(
    const ushort* __restrict__ po, const float2* __restrict__ pmd,
    ushort* __restrict__ O)
{
  int idx = blockIdx.x * 256 + threadIdx.x;  // 131072
  int d8 = idx & 7;
  int h = (idx >> 3) & 15;
  int r = idx >> 7;                // 0..1023
  int rb4 = 16 + (r >> 6), qi = r & 63;
  int base, ns;
  if (rb4 < 24) { base = (rb4 - 16) * 2; ns = 2; }
  else          { base = 16 + (rb4 - 24) * 3; ns = 3; }

  float2 md0 = pmd[(h * 40 + base + 0) * 64 + qi];
  float2 md1 = pmd[(h * 40 + base + 1) * 64 + qi];
  int i2 = (ns == 3) ? 2 : 0;
  float2 md2 = pmd[(h * 40 + base + i2) * 64 + qi];
  float m = fmaxf(fmaxf(md0.x, md1.x), (ns == 3) ? md2.x : -3e38f);
  float w0 = exp2f((md0.x - m) * C2);
  float w1 = exp2f((md1.x - m) * C2);
  float w2 = (ns == 3) ? exp2f((md2.x - m) * C2) : 0.f;
  float inv = 1.f / (md0.y * w0 + md1.y * w1 + md2.y * w2);

  const ushort* p0 = po + ((size_t)(h * 40 + base + 0) * 64 + qi) * 64 + d8 * 8;
  const ushort* p1 = po + ((size_t)(h * 40 + base + 1) * 64 + qi) * 64 + d8 * 8;
  const ushort* p2 = po + ((size_t)(h * 40 + base + i2) * 64 + qi) * 64 + d8 * 8;
  uint4 a = *(const uint4*)p0, b = *(const uint4*)p1, c = *(const uint4*)p2;
  const ushort* ap = (const ushort*)&a;
  const ushort* bp = (const ushort*)&b;
  const ushort* cp = (const ushort*)&c;
  ushort out8[8];
#pragma unroll
  for (int e = 0; e < 8; ++e)
    out8[e] = f2bf((bf2f(ap[e]) * w0 + bf2f(bp[e]) * w1 + bf2f(cp[e]) * w2) * inv);
  int q = rb4 * 64 + qi;
  *(uint4*)(O + (size_t)q * DMODEL + h * HDIM + d8 * 8) = *(const uint4*)out8;
}

// ---------------- launch ----------------
extern "C" void kernel_launch(void* const* d_in, const int* in_sizes, int n_in,
                              void* d_out, int out_size, void* d_ws, size_t ws_size,
                              hipStream_t stream) {
  const float* x     = (const float*)d_in[0];
  const float* w_in  = (const float*)d_in[1];
  const float* w_out = (const float*)d_in[2];
  const int* icausal = (const int*)d_in[3];

  char* ws = (char*)d_ws;
  ushort* xbf    = (ushort*)(ws);                  // 4MB (vt reuses)
  ushort* winbf  = (ushort*)(ws + 4194304);        // 6MB (po/pmd/tab reuse after gemm1)
  ushort* woutbf = (ushort*)(ws + 10485760);       // 2MB
  ushort* qkv    = (ushort*)(ws + 12582912);       // 12MB
  ushort* obuf   = (ushort*)(ws + 25165824);       // 4MB
  ushort* vt     = xbf;                            // 16*64*2048*2B = 4MB
  ushort* po     = winbf;                          // 16*40*64*64*2B = 5.24MB
  float2* pmd    = (float2*)(ws + 4194304 + 5242880);   // 327KB, ends 9764864
  float2* tab    = (float2*)(ws + 9764864);             // 512KB, ends < 10485760

  cvt_all<<<6144, 256, 0, stream>>>(x, w_in, w_out, xbf, winbf, woutbf);

  gemm_abt<128, 64, 1><<<16 * 48, 256, 0, stream>>>(xbf, winbf, (void*)qkv, 2048, 3072, 1024);
  rope_tab<<<256, 256, 0, stream>>>(tab);          // after gemm1: overwrites winbf tail
  rope_kernel<<<8192, 256, 0, stream>>>(qkv, tab);
  transpose_v<<<512, 256, 0, stream>>>(qkv, vt);
  attn_mfma<<<896, 256, 0, stream>>>(qkv, vt, obuf, po, pmd, icausal);
  attn_combine<<<512, 256, 0, stream>>>(po, pmd, obuf);
  gemm_abt<64, 64, 0><<<32 * 16, 256, 0, stream>>>(obuf, woutbf, d_out, 2048, 1024, 1024);
}

// Round 8
// 105.784 us; speedup vs baseline: 1.3135x; 1.3135x over previous
//
#include <hip/hip_runtime.h>
#include <stdint.h>

#define S_LEN 2048
#define DMODEL 1024
#define NHEAD 16
#define HDIM 64
#define NE 3072
#define C2 0.18033688011112042f  // 0.125 * log2(e)

typedef __attribute__((ext_vector_type(8))) short short8_t;
typedef __attribute__((ext_vector_type(4))) float f32x4;
typedef __attribute__((ext_vector_type(16))) float f32x16;

__device__ __forceinline__ float bf2f(ushort u) {
  union { float f; uint32_t i; } c; c.i = ((uint32_t)u) << 16; return c.f;
}
__device__ __forceinline__ ushort f2bf(float f) {
  union { float f; uint32_t i; } c; c.f = f;
  uint32_t x = c.i;
  return (ushort)((x + 0x7fffu + ((x >> 16) & 1u)) >> 16);
}

__device__ __forceinline__ void gload_lds16(const ushort* g, ushort* l) {
  __builtin_amdgcn_global_load_lds(
      (const __attribute__((address_space(1))) void*)g,
      (__attribute__((address_space(3))) void*)l, 16, 0, 0);
}

// ---------------- fused fp32 -> bf16 convert (x, w_in, w_out) ----------------
__global__ void cvt_all(const float* __restrict__ x, const float* __restrict__ w_in,
                        const float* __restrict__ w_out,
                        ushort* __restrict__ xbf, ushort* __restrict__ winbf,
                        ushort* __restrict__ woutbf) {
  int i = blockIdx.x * blockDim.x + threadIdx.x;
  const float* src; ushort* dst; int off;
  if (i < 524288)       { src = x;     dst = xbf;    off = i; }
  else if (i < 1310720) { src = w_in;  dst = winbf;  off = i - 524288; }
  else                  { src = w_out; dst = woutbf; off = i - 1310720; }
  float4 v = ((const float4*)src)[off];
  ushort4 o;
  o.x = f2bf(v.x); o.y = f2bf(v.y); o.z = f2bf(v.z); o.w = f2bf(v.w);
  ((ushort4*)dst)[off] = o;
}

// ---------------- bf16 GEMM: C[M][N] = A[M][K] * B[N][K]^T ----------------
template<int BM, int BN, int OUT_BF16>
__global__ __launch_bounds__(256) void gemm_abt(
    const ushort* __restrict__ A, const ushort* __restrict__ B,
    void* __restrict__ Cv, int M, int N, int K)
{
  constexpr int AR = BM / 32;
  constexpr int AC = BN / 32;
  constexpr int NG = (BM + BN) / 16;
  constexpr int PG = NG / 4;
  __shared__ ushort lds[(BM + BN) * 32];

  const int nbn = N / BN;
  const int cpx = gridDim.x >> 3;
  const int bid = blockIdx.x;
  const int swz = (bid & 7) * cpx + (bid >> 3);
  const int bm = swz / nbn;
  const int bn = swz - bm * nbn;
  const int tid = threadIdx.x;
  const int w = tid >> 6, l = tid & 63;
  const int wm = w >> 1, wn = w & 1;
  const int fr = l & 15, fg = l >> 4;

  f32x4 acc[AR][AC];
#pragma unroll
  for (int r = 0; r < AR; ++r)
#pragma unroll
    for (int c = 0; c < AC; ++c) acc[r][c] = (f32x4){0.f, 0.f, 0.f, 0.f};

  const ushort* gsrc[PG];
  ushort* ldst[PG];
#pragma unroll
  for (int i = 0; i < PG; ++i) {
    int c = w + 4 * i;
    if (c < BM / 16) {
      gsrc[i] = A + (size_t)(bm * BM + c * 16 + (l >> 2)) * K + (l & 3) * 8;
      ldst[i] = &lds[c * 512];
    } else {
      int c2 = c - BM / 16;
      gsrc[i] = B + (size_t)(bn * BN + c2 * 16 + (l >> 2)) * K + (l & 3) * 8;
      ldst[i] = &lds[BM * 32 + c2 * 512];
    }
  }

  const ushort* fa = &lds[(wm * (BM / 2) + fr) * 32 + fg * 8];
  const ushort* fb = &lds[BM * 32 + (wn * (BN / 2) + fr) * 32 + fg * 8];

  for (int k0 = 0; k0 < K; k0 += 32) {
    __syncthreads();
#pragma unroll
    for (int i = 0; i < PG; ++i) gload_lds16(gsrc[i] + k0, ldst[i]);
    __syncthreads();

    short8_t af[AR], bfr[AC];
#pragma unroll
    for (int r = 0; r < AR; ++r) {
      union { short8_t v; uint4 q; } u;
      u.q = *(const uint4*)(fa + r * 512);
      af[r] = u.v;
    }
#pragma unroll
    for (int c = 0; c < AC; ++c) {
      union { short8_t v; uint4 q; } u;
      u.q = *(const uint4*)(fb + c * 512);
      bfr[c] = u.v;
    }
    __builtin_amdgcn_s_setprio(1);
#pragma unroll
    for (int r = 0; r < AR; ++r)
#pragma unroll
      for (int c = 0; c < AC; ++c)
        acc[r][c] = __builtin_amdgcn_mfma_f32_16x16x32_bf16(af[r], bfr[c], acc[r][c], 0, 0, 0);
    __builtin_amdgcn_s_setprio(0);
  }

  const int row0 = bm * BM + wm * (BM / 2) + fg * 4;
  const int col0 = bn * BN + wn * (BN / 2) + fr;
#pragma unroll
  for (int r = 0; r < AR; ++r)
#pragma unroll
    for (int c = 0; c < AC; ++c)
#pragma unroll
      for (int j = 0; j < 4; ++j) {
        int row = row0 + r * 16 + j;
        int col = col0 + c * 16;
        if (OUT_BF16)
          ((ushort*)Cv)[(size_t)row * N + col] = f2bf(acc[r][c][j]);
        else
          ((float*)Cv)[(size_t)row * N + col] = acc[r][c][j];
      }
}

// ---------------- RoPE in-place on Q and K sections of qkv ----------------
__global__ void rope_kernel(ushort* __restrict__ qkv) {
  int idx = blockIdx.x * blockDim.x + threadIdx.x;
  int i = idx & 31;
  int hh = (idx >> 5) & (NHEAD - 1);
  int sec = (idx >> 9) & 1;
  int srow = idx >> 10;
  float invf = exp2f((float)i * (-13.287712379549449f / 32.f));
  float ang = (float)srow * invf;
  float sn, c;
  sincosf(ang, &sn, &c);
  size_t base = (size_t)srow * NE + (size_t)sec * DMODEL + hh * HDIM;
  float x1 = bf2f(qkv[base + i]);
  float x2 = bf2f(qkv[base + i + 32]);
  qkv[base + i]      = f2bf(x1 * c - x2 * sn);
  qkv[base + i + 32] = f2bf(x2 * c + x1 * sn);
}

// ---------------- V transpose: qkv V-section -> vt[h][d][key] ----------------
__global__ __launch_bounds__(256) void transpose_v(
    const ushort* __restrict__ qkv, ushort* __restrict__ vt)
{
  __shared__ ushort t[64][72];
  const int h = blockIdx.x & 15, c = blockIdx.x >> 4;
  const int tid = threadIdx.x;
#pragma unroll
  for (int j = 0; j < 2; ++j) {
    int idx = tid + 256 * j;
    int key = idx >> 3, d8 = (idx & 7) << 3;
    uint4 v = *(const uint4*)(qkv + (size_t)(c * 64 + key) * NE + 2 * DMODEL + h * HDIM + d8);
    *(uint4*)&t[key][d8] = v;
  }
  __syncthreads();
#pragma unroll
  for (int j = 0; j < 2; ++j) {
    int idx = tid + 256 * j;
    int d = idx >> 3, k8 = (idx & 7) << 3;
    ushort tmp[8];
#pragma unroll
    for (int i = 0; i < 8; ++i) tmp[i] = t[k8 + i][d];
    *(uint4*)(vt + (size_t)(h * 64 + d) * S_LEN + c * 64 + k8) = *(const uint4*)tmp;
  }
}

// ---------------- MFMA flash attention: 32x32 fragments, in-register P ----------------
// 896 blocks = 56 items x 16 heads, 2 waves/block, 32 q-rows/wave (64/block).
// QK^T = mfma32(K,Q) -> lane owns all 64 scores of q=l&31 (two kh halves);
// P redistributed to PV B-frags via cvt_pk + shfl_xor(32):
//   for slice ks, lane (q,hi) needs regs kp..kp+3 (kp=8*(ks&1)) of BOTH hi-halves
//   shifted by 4*hi -- pack own wL(kp+0..3)/wH(kp+4..7), swap hi?wL:wH.
__global__ __launch_bounds__(128) void attn_mfma(
    const ushort* __restrict__ qkv, const ushort* __restrict__ vt,
    ushort* __restrict__ O, ushort* __restrict__ po, float2* __restrict__ pmd,
    const int* __restrict__ icausal)
{
  __shared__ __align__(16) ushort SMEM[16384];  // 32KB: K[2][4096], V[2][4096]
  ushort* const K0 = SMEM;
  ushort* const V0 = SMEM + 8192;

  const int h = blockIdx.x & 15;
  const int i = blockIdx.x >> 4;
  const int j = (i < 8) ? (15 - i) : (i < 48) ? (63 - i) : (55 - i);  // longest-first
  int rb4, ns, s;
  if (j < 16)      { rb4 = j; ns = 1; s = 0; }
  else if (j < 32) { rb4 = 16 + ((j - 16) >> 1); ns = 2; s = (j - 16) & 1; }
  else             { int jj = j - 32; int q3 = jj / 3; rb4 = 24 + q3; ns = 3; s = jj - q3 * 3; }

  const int causal = *icausal;
  const int nt = causal ? (rb4 + 1) : (S_LEN / 64);
  const int t0 = s * nt / ns, t1 = (s + 1) * nt / ns;

  const int tid = threadIdx.x;
  const int w = tid >> 6, l = tid & 63;
  const int q = l & 31, hi = l >> 5;
  const int q0 = rb4 * 64 + w * 32;   // this wave's first q row
  const int qa = q0 + q;              // this lane's absolute q row
  const int xsw = (q & 7) << 4;

  // Q B-fragments: qf[ks] = Q[qa][16*ks + 8*hi + 0..7]
  short8_t qf[4];
  {
    const ushort* qp = qkv + (size_t)qa * NE + h * HDIM + 8 * hi;
#pragma unroll
    for (int ks = 0; ks < 4; ++ks) {
      union { short8_t v; uint4 u; } uu;
      uu.u = *(const uint4*)(qp + 16 * ks);
      qf[ks] = uu.v;
    }
  }

  // staging: 128 threads x 4 chunks each for K and V (16KB/tile)
  const int srow = tid >> 3;
  const int cb = (tid & 7) ^ (srow & 7);
  const ushort* ksrc = qkv + (size_t)(t0 * 64 + srow) * NE + DMODEL + h * HDIM + cb * 8;
  const ushort* vsrc = vt + (size_t)(h * 64 + srow) * S_LEN + t0 * 64 + cb * 8;

  auto stage = [&](int b) {
#pragma unroll
    for (int ii = 0; ii < 4; ++ii) {
      gload_lds16(ksrc + (size_t)ii * 16 * NE,    K0 + b * 4096 + tid * 8 + ii * 1024);
      gload_lds16(vsrc + (size_t)ii * 16 * S_LEN, V0 + b * 4096 + tid * 8 + ii * 1024);
    }
    ksrc += (size_t)64 * NE;
    vsrc += 64;
  };

  float m_run = -1e30f, den = 0.f;
  f32x16 oacc[2];
#pragma unroll
  for (int d = 0; d < 2; ++d)
#pragma unroll
    for (int r = 0; r < 16; ++r) oacc[d][r] = 0.f;

  stage(0);
  __syncthreads();
  int buf = 0;

  for (int t = t0; t < t1; ++t) {
    const int k0 = t * 64;
    if (t + 1 < t1) stage(buf ^ 1);

    // ---- QK^T: sacc[kh] = S[32*kh + key'][q], contract d=64 in 4 slices ----
    const char* Kb = (const char*)(K0 + buf * 4096);
    f32x16 sacc[2];
#pragma unroll
    for (int kh = 0; kh < 2; ++kh)
#pragma unroll
      for (int r = 0; r < 16; ++r) sacc[kh][r] = 0.f;
    __builtin_amdgcn_s_setprio(1);
#pragma unroll
    for (int ks = 0; ks < 4; ++ks)
#pragma unroll
      for (int kh = 0; kh < 2; ++kh) {
        int off = (((32 * kh + q) * 128) + 32 * ks + 16 * hi) ^ xsw;
        union { short8_t v; uint4 u; } ku;
        ku.u = *(const uint4*)(Kb + off);
        sacc[kh] = __builtin_amdgcn_mfma_f32_32x32x16_bf16(ku.v, qf[ks], sacc[kh], 0, 0, 0);
      }
    __builtin_amdgcn_s_setprio(0);

    // ---- mask + max (lane holds 32 scores of q; keys split across hi) ----
    float vmax = -3e38f;
    const bool domask = causal && (t == rb4);
#pragma unroll
    for (int kh = 0; kh < 2; ++kh)
#pragma unroll
      for (int r = 0; r < 16; ++r) {
        float sv = sacc[kh][r];
        if (domask && (k0 + 32 * kh + (r & 3) + 8 * (r >> 2) + 4 * hi > qa)) sv = -3e38f;
        sacc[kh][r] = sv;
        vmax = fmaxf(vmax, sv);
      }
    vmax = fmaxf(vmax, __shfl_xor(vmax, 32));

    // defer-rescale (T13)
    if (__any(vmax > m_run + 44.3614196f)) {   // 8 / C2
      float mn = fmaxf(m_run, vmax);
      float alpha = exp2f((m_run - mn) * C2);
      den *= alpha;
#pragma unroll
      for (int d = 0; d < 2; ++d)
#pragma unroll
        for (int r = 0; r < 16; ++r) oacc[d][r] *= alpha;
      m_run = mn;
    }
    float mc2 = m_run * C2;
    float psum = 0.f;
#pragma unroll
    for (int kh = 0; kh < 2; ++kh)
#pragma unroll
      for (int r = 0; r < 16; ++r) {
        float p = exp2f(fmaf(sacc[kh][r], C2, -mc2));
        psum += p;
        sacc[kh][r] = p;
      }
    psum += __shfl_xor(psum, 32);
    den += psum;

    // ---- build PV B-frags in registers: pa[ks][j] = P[16*ks + 8*hi + j][q] ----
    short8_t pa[4];
#pragma unroll
    for (int ks = 0; ks < 4; ++ks) {
      const int blk = ks >> 1, kp = (ks & 1) * 8;
      uint wL0, wL1, wH0, wH1;
      asm("v_cvt_pk_bf16_f32 %0, %1, %2" : "=v"(wL0) : "v"(sacc[blk][kp + 0]), "v"(sacc[blk][kp + 1]));
      asm("v_cvt_pk_bf16_f32 %0, %1, %2" : "=v"(wL1) : "v"(sacc[blk][kp + 2]), "v"(sacc[blk][kp + 3]));
      asm("v_cvt_pk_bf16_f32 %0, %1, %2" : "=v"(wH0) : "v"(sacc[blk][kp + 4]), "v"(sacc[blk][kp + 5]));
      asm("v_cvt_pk_bf16_f32 %0, %1, %2" : "=v"(wH1) : "v"(sacc[blk][kp + 6]), "v"(sacc[blk][kp + 7]));
      uint s0 = hi ? wL0 : wH0, s1 = hi ? wL1 : wH1;
      uint r0 = __shfl_xor(s0, 32), r1 = __shfl_xor(s1, 32);
      union { short8_t v; uint u[4]; } pu;
      pu.u[0] = hi ? r0 : wL0;
      pu.u[1] = hi ? r1 : wL1;
      pu.u[2] = hi ? wH0 : r0;
      pu.u[3] = hi ? wH1 : r1;
      pa[ks] = pu.v;
    }

    // ---- PV: oacc[dh] = O^T[32*dh + d'][q] ----
    const char* Vb = (const char*)(V0 + buf * 4096);
    __builtin_amdgcn_s_setprio(1);
#pragma unroll
    for (int ks = 0; ks < 4; ++ks)
#pragma unroll
      for (int dh = 0; dh < 2; ++dh) {
        int off = (((32 * dh + q) * 128) + 32 * ks + 16 * hi) ^ xsw;
        union { short8_t v; uint4 u; } vu;
        vu.u = *(const uint4*)(Vb + off);
        oacc[dh] = __builtin_amdgcn_mfma_f32_32x32x16_bf16(vu.v, pa[ks], oacc[dh], 0, 0, 0);
      }
    __builtin_amdgcn_s_setprio(0);

    __syncthreads();
    buf ^= 1;
  }

  // ---- epilogue: bounce O through freed K-LDS, coalesced row writes ----
  const float scale = (ns > 1) ? 1.f : (1.f / den);
  char* const Ob = (char*)SMEM + w * 4096;   // wave-private 4KB in K area
#pragma unroll
  for (int dh = 0; dh < 2; ++dh)
#pragma unroll
    for (int m = 0; m < 4; ++m) {
      uint a0, a1;
      float e0 = oacc[dh][4 * m + 0] * scale, e1 = oacc[dh][4 * m + 1] * scale;
      float e2 = oacc[dh][4 * m + 2] * scale, e3 = oacc[dh][4 * m + 3] * scale;
      asm("v_cvt_pk_bf16_f32 %0, %1, %2" : "=v"(a0) : "v"(e0), "v"(e1));
      asm("v_cvt_pk_bf16_f32 %0, %1, %2" : "=v"(a1) : "v"(e2), "v"(e3));
      uint2 dd; dd.x = a0; dd.y = a1;
      *(uint2*)(Ob + ((q * 128 + 64 * dh + 16 * m + 8 * hi) ^ xsw)) = dd;
    }

  if (ns > 1) {
    const int slot = (rb4 < 24) ? ((rb4 - 16) * 2 + s) : (16 + (rb4 - 24) * 3 + s);
#pragma unroll
    for (int jj = 0; jj < 4; ++jj) {
      int q2 = (l >> 3) + 8 * jj, seg = l & 7;
      uint4 val = *(const uint4*)(Ob + ((q2 * 128 + seg * 16) ^ ((q2 & 7) << 4)));
      *(uint4*)(po + ((size_t)(h * 40 + slot) * 64 + w * 32 + q2) * 64 + seg * 8) = val;
    }
    if (l < 32) pmd[(h * 40 + slot) * 64 + w * 32 + l] = make_float2(m_run, den);
  } else {
#pragma unroll
    for (int jj = 0; jj < 4; ++jj) {
      int q2 = (l >> 3) + 8 * jj, seg = l & 7;
      uint4 val = *(const uint4*)(Ob + ((q2 * 128 + seg * 16) ^ ((q2 & 7) << 4)));
      *(uint4*)(O + (size_t)(q0 + q2) * DMODEL + h * HDIM + seg * 8) = val;
    }
  }
}

// ---------------- combine key-slices for q rows 1024..2047 ----------------
__global__ __launch_bounds__(256) void attn_combine(
    const ushort* __restrict__ po, const float2* __restrict__ pmd,
    ushort* __restrict__ O)
{
  int idx = blockIdx.x * 256 + threadIdx.x;  // 131072
  int d8 = idx & 7;
  int h = (idx >> 3) & 15;
  int r = idx >> 7;                // 0..1023
  int rb4 = 16 + (r >> 6), qi = r & 63;
  int base, ns;
  if (rb4 < 24) { base = (rb4 - 16) * 2; ns = 2; }
  else          { base = 16 + (rb4 - 24) * 3; ns = 3; }

  float2 md0 = pmd[(h * 40 + base + 0) * 64 + qi];
  float2 md1 = pmd[(h * 40 + base + 1) * 64 + qi];
  int i2 = (ns == 3) ? 2 : 0;
  float2 md2 = pmd[(h * 40 + base + i2) * 64 + qi];
  float m = fmaxf(fmaxf(md0.x, md1.x), (ns == 3) ? md2.x : -3e38f);
  float w0 = exp2f((md0.x - m) * C2);
  float w1 = exp2f((md1.x - m) * C2);
  float w2 = (ns == 3) ? exp2f((md2.x - m) * C2) : 0.f;
  float inv = 1.f / (md0.y * w0 + md1.y * w1 + md2.y * w2);

  const ushort* p0 = po + ((size_t)(h * 40 + base + 0) * 64 + qi) * 64 + d8 * 8;
  const ushort* p1 = po + ((size_t)(h * 40 + base + 1) * 64 + qi) * 64 + d8 * 8;
  const ushort* p2 = po + ((size_t)(h * 40 + base + i2) * 64 + qi) * 64 + d8 * 8;
  uint4 a = *(const uint4*)p0, b = *(const uint4*)p1, c = *(const uint4*)p2;
  const ushort* ap = (const ushort*)&a;
  const ushort* bp = (const ushort*)&b;
  const ushort* cp = (const ushort*)&c;
  ushort out8[8];
#pragma unroll
  for (int e = 0; e < 8; ++e)
    out8[e] = f2bf((bf2f(ap[e]) * w0 + bf2f(bp[e]) * w1 + bf2f(cp[e]) * w2) * inv);
  int qq = rb4 * 64 + qi;
  *(uint4*)(O + (size_t)qq * DMODEL + h * HDIM + d8 * 8) = *(const uint4*)out8;
}

// ---------------- launch ----------------
extern "C" void kernel_launch(void* const* d_in, const int* in_sizes, int n_in,
                              void* d_out, int out_size, void* d_ws, size_t ws_size,
                              hipStream_t stream) {
  const float* x     = (const float*)d_in[0];
  const float* w_in  = (const float*)d_in[1];
  const float* w_out = (const float*)d_in[2];
  const int* icausal = (const int*)d_in[3];

  char* ws = (char*)d_ws;
  ushort* xbf    = (ushort*)(ws);                  // 4MB (vt reuses)
  ushort* winbf  = (ushort*)(ws + 4194304);        // 6MB (po/pmd reuse after gemm1)
  ushort* woutbf = (ushort*)(ws + 10485760);       // 2MB
  ushort* qkv    = (ushort*)(ws + 12582912);       // 12MB
  ushort* obuf   = (ushort*)(ws + 25165824);       // 4MB
  ushort* vt     = xbf;                            // 16*64*2048*2B = 4MB
  ushort* po     = winbf;                          // 16*40*64*64*2B = 5.24MB
  float2* pmd    = (float2*)(ws + 4194304 + 5242880);  // 327KB (within winbf 6MB)

  cvt_all<<<6144, 256, 0, stream>>>(x, w_in, w_out, xbf, winbf, woutbf);

  gemm_abt<128, 64, 1><<<16 * 48, 256, 0, stream>>>(xbf, winbf, (void*)qkv, 2048, 3072, 1024);
  rope_kernel<<<8192, 256, 0, stream>>>(qkv);
  transpose_v<<<512, 256, 0, stream>>>(qkv, vt);
  attn_mfma<<<896, 128, 0, stream>>>(qkv, vt, obuf, po, pmd, icausal);
  attn_combine<<<512, 256, 0, stream>>>(po, pmd, obuf);
  gemm_abt<64, 64, 0><<<32 * 16, 256, 0, stream>>>(obuf, woutbf, d_out, 2048, 1024, 1024);
}